// Round 2
// baseline (277.134 us; speedup 1.0000x reference)
//
#include <hip/hip_runtime.h>
#include <math.h>

#define NCLS 20
#define IGNORE_IDX 255
#define LOG2E 1.4426950408889634f
#define NTHR 256
#define VOXPT 4   // voxels per thread (grid-stride within block)
#define NSLOT 32  // partial-sum slots (rows of 64 floats) to spread atomic chains

__device__ __forceinline__ float wave_reduce(float v) {
#pragma unroll
  for (int off = 32; off > 0; off >>= 1) v += __shfl_xor(v, off, 64);
  return v;
}

__device__ __forceinline__ float neg_log_clamped(float x, bool cond) {
  if (!cond) return 0.0f;
  float xs = fmaxf(x, 1e-38f);
  return fminf(-logf(xs), 100.0f);
}

// Layout of s_acc / ws columns: [0..19] sum_p, [20..39] nominator,
// [40..59] ct_count, [60..63] unused.
//
// Design notes (r1, resubmitted r2 after infra-only bench failure):
//  - 1 voxel per LANE (scalar f32 loads, 256B/wave-instr, fully coalesced).
//    e[20] = 20 VGPRs instead of 80 (v4f version spilled to AGPRs: reported
//    VGPR=68 < 80 live => hidden AGPR spill => 23% occupancy, 0.9 TB/s).
//  - sum_p accumulated in 20 STATIC-indexed register accumulators across
//    VOXPT voxels; flushed once per thread via no-return ds_add_f32.
//  - All LDS accumulation is fire-and-forget atomics into [row][lane&31]
//    slots (bank = lane&31 -> at worst 2-way conflict, no dependent chains).
//    No wave butterflies in pass1 (were 120 dependent DS ops/thread).
//  - __launch_bounds__(256,6): cap 85 VGPR -> 24 waves/CU, ~20 loads/wave
//    in flight ~= 120 KB/CU outstanding -> HBM-saturating.
__global__ __launch_bounds__(NTHR, 6) void pass1(const float* __restrict__ pred,
                                                 const int* __restrict__ target,
                                                 float* __restrict__ ws, int N) {
  __shared__ float s_acc[3 * NCLS][32];
  const int tid = threadIdx.x;
  const int sl = tid & 31;

  {
    float* p = &s_acc[0][0];
    for (int i = tid; i < 3 * NCLS * 32; i += NTHR) p[i] = 0.0f;
  }
  __syncthreads();

  float accp[NCLS];
#pragma unroll
  for (int c = 0; c < NCLS; ++c) accp[c] = 0.0f;

  const int base = blockIdx.x * (NTHR * VOXPT);
#pragma unroll 1  // keep voxel iterations sequential: bounds register pressure
  for (int it = 0; it < VOXPT; ++it) {
    const int n = base + it * NTHR + tid;
    if (n < N) {
      const int t = target[n];
      float e[NCLS];
      float Z = 0.0f;
      float pt = 0.0f;
#pragma unroll
      for (int c = 0; c < NCLS; ++c) {
        const float x = pred[(size_t)c * N + n];
        e[c] = __builtin_amdgcn_exp2f(fminf(x, 80.0f) * LOG2E);
        Z += e[c];
        pt = (c == t) ? e[c] : pt;
      }
      const bool msk = (t != IGNORE_IDX);
      const float w = msk ? __builtin_amdgcn_rcpf(Z) : 0.0f;
#pragma unroll
      for (int c = 0; c < NCLS; ++c) accp[c] += e[c] * w;
      if (msk) {
        atomicAdd(&s_acc[NCLS + t][sl], pt * w);      // nominator
        atomicAdd(&s_acc[2 * NCLS + t][sl], 1.0f);    // ct_count
      }
    }
  }

  // flush per-thread register partials (no-return ds_add_f32, 2-way max)
#pragma unroll
  for (int c = 0; c < NCLS; ++c) atomicAdd(&s_acc[c][sl], accp[c]);
  __syncthreads();

  // block flush: 60 rows x 32 slots. Rotated start so lane r hits bank
  // (i+r)&31 -> all active lanes on distinct banks each iteration.
  if (tid < 3 * NCLS) {
    const float* row = s_acc[tid];
    float v = 0.0f;
#pragma unroll
    for (int i = 0; i < 32; ++i) v += row[(i + tid) & 31];
    // relaxed global atomics; pass2 is a separate dispatch (kernel boundary
    // provides visibility). 32 slots -> chains of gridDim/32 per address.
    atomicAdd(&ws[(size_t)(blockIdx.x & (NSLOT - 1)) * 64 + tid], v);
  }
}

__global__ __launch_bounds__(64) void pass2(const float* __restrict__ ws,
                                            float* __restrict__ out) {
  __shared__ float s[64];
  const int lane = threadIdx.x;
  float a = 0.0f;
#pragma unroll
  for (int r = 0; r < NSLOT; ++r) a += ws[r * 64 + lane];  // 32 indep loads

  // n_masked = sum of ct_count columns (lanes 40..59), uniform collective
  const float n_masked =
      wave_reduce((lane >= 2 * NCLS && lane < 3 * NCLS) ? a : 0.0f);

  // LDS bounce for per-class gather — NO divergent cross-lane ops
  s[lane] = a;
  __syncthreads();

  float loss = 0.0f, validf = 0.0f;
  if (lane < NCLS) {
    const float sump = s[lane];
    const float nom = s[NCLS + lane];
    const float cnt = s[2 * NCLS + lane];
    const bool valid = cnt > 0.0f;
    const float prec = nom / fmaxf(sump, 1e-38f);
    const float rec = nom / fmaxf(cnt, 1.0f);
    const float negc = n_masked - cnt;
    const float specn = n_masked - sump - cnt + nom;
    const float spec = specn / fmaxf(negc, 1.0f);
    loss = neg_log_clamped(prec, valid && (sump > 0.0f)) +
           neg_log_clamped(rec, valid) +
           neg_log_clamped(spec, valid && (negc > 0.0f));
    validf = valid ? 1.0f : 0.0f;
  }
  loss = wave_reduce(loss);      // uniform: all 64 lanes participate
  validf = wave_reduce(validf);
  if (lane == 0) out[0] = loss / validf;
}

extern "C" void kernel_launch(void* const* d_in, const int* in_sizes, int n_in,
                              void* d_out, int out_size, void* d_ws, size_t ws_size,
                              hipStream_t stream) {
  const float* pred = (const float*)d_in[0];
  const int* target = (const int*)d_in[1];
  const int N = in_sizes[1];  // voxel count; C = in_sizes[0]/N = 20
  const int per_blk = NTHR * VOXPT;                 // 1024 voxels per block
  const int nblk = (N + per_blk - 1) / per_blk;     // 2048 for N = 2^21

  hipMemsetAsync(d_ws, 0, NSLOT * 64 * sizeof(float), stream);
  pass1<<<nblk, NTHR, 0, stream>>>(pred, target, (float*)d_ws, N);
  pass2<<<1, 64, 0, stream>>>((const float*)d_ws, (float*)d_out);
}